// Round 3
// baseline (164.495 us; speedup 1.0000x reference)
//
#include <hip/hip_runtime.h>
#include <hip/hip_bf16.h>

namespace {
constexpr int N_ = 4, H_ = 512, W_ = 512, K_ = 4;
constexpr float SIGMA_ = 1e-4f;
constexpr float GAMMA_ = 1e-4f;
constexpr float EPS_   = 1e-10f;
constexpr float ZNEAR_ = 1.0f, ZFAR_ = 100.0f;
} // namespace

// Dtype model (evidence chain):
//   r1: floats read as bf16 -> NaN (fp32 mantissa words as bf16 exps) => inputs fp32
//   r2: absmax 2.0039 > 2.0 with unit outputs => harness reads output as fp32,
//       my bf16 writes were misparsed => OUTPUT fp32
//   => fp32 inputs, int32 indices, fp32 output.
// One thread per pixel (P = N*H*W = 1,048,576):
//   pix_to_face [P,4] int32   -> int4 load (16B/lane, coalesced)
//   dists,zbuf  [P,4] fp32    -> float4 load (16B/lane)
//   bary        [P,4,3] fp32  -> conditional scalar loads (only contributing k)
//   faces [F,3] int32 (2.4MB), vnorm [V,3] fp32 (1.2MB) -> L2-resident gathers
__global__ __launch_bounds__(256) void normal_shader_kernel(
    const float* __restrict__ vnorm,
    const float* __restrict__ bary,
    const float* __restrict__ dists,
    const float* __restrict__ zbuf,
    const int*   __restrict__ faces,
    const int*   __restrict__ ptf,
    float*       __restrict__ out,
    int P)
{
    const int p = blockIdx.x * blockDim.x + threadIdx.x;
    if (p >= P) return;

    const int4   f4 = reinterpret_cast<const int4*>(ptf)[p];
    const int fidx[4] = {f4.x, f4.y, f4.z, f4.w};

    const float4 dv = reinterpret_cast<const float4*>(dists)[p];
    const float4 zv = reinterpret_cast<const float4*>(zbuf)[p];
    const float d[4] = {dv.x, dv.y, dv.z, dv.w};
    const float z[4] = {zv.x, zv.y, zv.z, zv.w};

    float prob[4], zinv[4];
    float zmax = EPS_;
#pragma unroll
    for (int k = 0; k < K_; ++k) {
        const bool valid = fidx[k] >= 0;
        // sigmoid(-d/sigma) = 1/(1+exp(d/sigma)); masked to 0 when invalid
        prob[k] = valid ? 1.0f / (1.0f + __expf(d[k] * (1.0f / SIGMA_))) : 0.0f;
        zinv[k] = valid ? (ZFAR_ - z[k]) * (1.0f / (ZFAR_ - ZNEAR_)) : 0.0f;
        zmax = fmaxf(zmax, zinv[k]);
    }
    const float delta = fmaxf(__expf((EPS_ - zmax) * (1.0f / GAMMA_)), EPS_);

    float acc0 = 0.f, acc1 = 0.f, acc2 = 0.f, wsum = 0.f;
#pragma unroll
    for (int k = 0; k < K_; ++k) {
        const float wn = prob[k] * __expf((zinv[k] - zmax) * (1.0f / GAMMA_));
        wsum += wn;
        // wn == 0 (invalid face, or exp underflow: zinv < zmax - ~0.0087)
        // contributes exactly 0 in the reference too -> skipping the gathers is
        // bit-equivalent. ~1 of 4 faces survives the /1e-4 softmax.
        if (wn != 0.0f) {
            const int* fv = faces + 3 * (size_t)fidx[k];
            const int v0 = fv[0], v1 = fv[1], v2 = fv[2];

            const float* bp = bary + ((size_t)p * 4 + k) * 3;
            const float b0 = bp[0], b1 = bp[1], b2 = bp[2];

            const float* n0 = vnorm + 3 * (size_t)v0;
            const float* n1 = vnorm + 3 * (size_t)v1;
            const float* n2 = vnorm + 3 * (size_t)v2;

            acc0 += wn * (b0 * n0[0] + b1 * n1[0] + b2 * n2[0]);
            acc1 += wn * (b0 * n0[1] + b1 * n1[1] + b2 * n2[1]);
            acc2 += wn * (b0 * n0[2] + b1 * n1[2] + b2 * n2[2]);
        }
    }

    const float inv_denom = 1.0f / (wsum + delta);
    const float r0 = (acc0 + delta) * inv_denom;   // bg = (1,1,1)
    const float r1 = (acc1 + delta) * inv_denom;
    const float r2 = (acc2 + delta) * inv_denom;
    const float nrm = fmaxf(sqrtf(r0 * r0 + r1 * r1 + r2 * r2), 1e-12f);
    const float inv = 1.0f / nrm;

    float* op = out + (size_t)p * 3;
    op[0] = r0 * inv;
    op[1] = r1 * inv;
    op[2] = r2 * inv;
}

extern "C" void kernel_launch(void* const* d_in, const int* in_sizes, int n_in,
                              void* d_out, int out_size, void* d_ws, size_t ws_size,
                              hipStream_t stream) {
    // setup_inputs order: verts(0, unused), vertex_normals(1), bary_coords(2),
    // dists(3), zbuf(4), faces(5), pix_to_face(6)
    const float* vnorm = (const float*)d_in[1];
    const float* bary  = (const float*)d_in[2];
    const float* dists = (const float*)d_in[3];
    const float* zbuf  = (const float*)d_in[4];
    const int*   faces = (const int*)d_in[5];
    const int*   ptf   = (const int*)d_in[6];
    float*       out   = (float*)d_out;

    const int P = N_ * H_ * W_;
    const dim3 block(256);
    const dim3 grid((P + block.x - 1) / block.x);
    hipLaunchKernelGGL(normal_shader_kernel, grid, block, 0, stream,
                       vnorm, bary, dists, zbuf, faces, ptf, out, P);
}